// Round 13
// baseline (240.059 us; speedup 1.0000x reference)
//
#include <hip/hip_runtime.h>
#include <stdint.h>

// HierarchicalZ2_12Quantizer on MI355X (gfx950) — producer/consumer wave pipeline.
// tokens = 8*4096 = 32768, D = 1024
// R12 post-mortem: only 128 tokens/CU exist -> per-wave 2-tile pipelining halves
// occupancy (4 waves/CU, 131us). R13: ONE 512-thr block/CU (grid 256, 105KB LDS):
//   waves 0-3 = producers: down-proj tile s (K-split 256 cols/wave, DMA staging,
//               P partials -> LDS dbuf), 8 tiles sequentially.
//   waves 4-7 = consumers: quantize tile s-1 (redundant per wave) + epilogue
//               (col-split 256/wave, L2-hot x loads, out stores).
// 9-step pipeline, raw s_barrier + lgkmcnt(0) ONLY (no vmcnt drain -> producer
// DMA and consumer stores stay in flight across barriers). HBM reads (producers)
// and writes (consumers) overlap for ~7/9 of the kernel.
// codes from bit patterns: c[j][i] = ((j>>(n-1-i))&1)?+1:-1.

#define DM 1024
#define OUT_OFF ((size_t)33554432)  // 8*4096*1024
#define NTOK 32768
#define NSLOT 32
#define WSA_OFF 32768               // float offset of gate-acc in ws

#define POFF 65536                  // P partials: 2 sets x 4 waves x [16][34] f32
#define VOFF 82944                  // V: 4 consumer waves x [16][40] bf16
#define COFF 88064                  // C: 4 consumer waves x [16][68] f32
// total LDS = 105472 B

typedef float f32x4 __attribute__((ext_vector_type(4)));
typedef short bf16x8 __attribute__((ext_vector_type(8)));

typedef const __attribute__((address_space(1))) unsigned int* gas1_t;
typedef __attribute__((address_space(3))) unsigned int* las3_t;

__device__ __forceinline__ void gl_lds16(const void* g, void* l){
  __builtin_amdgcn_global_load_lds((gas1_t)g, (las3_t)l, 16, 0, 0);
}

__device__ __forceinline__ short f2bf(float f){
  unsigned u = __builtin_bit_cast(unsigned, f);
  unsigned r = u + 0x7fffu + ((u >> 16) & 1u);   // round-to-nearest-even
  return (short)(r >> 16);
}

// soft_quantize over the 2^NB hypercube corners; z[NB] -> q[NB]
template<int NB>
__device__ __forceinline__ void softq(const float* z, float invt, float* q){
  constexpr int K = 1 << NB;
  float d[K];
  float dmin = 3.4e38f;
#pragma unroll
  for (int j = 0; j < K; ++j){
    float acc = 0.f;
#pragma unroll
    for (int i = 0; i < NB; ++i){
      float c = ((j >> (NB-1-i)) & 1) ? 1.f : -1.f;
      float t = z[i] - c;
      acc = fmaf(t, t, acc);
    }
    float dj = sqrtf(acc);
    d[j] = dj;
    dmin = fminf(dmin, dj);
  }
  float S = 0.f;
  float s1[NB];
#pragma unroll
  for (int i = 0; i < NB; ++i) s1[i] = 0.f;
#pragma unroll
  for (int j = 0; j < K; ++j){
    float wj = __expf((dmin - d[j]) * invt);
    S += wj;
#pragma unroll
    for (int i = 0; i < NB; ++i)
      if ((j >> (NB-1-i)) & 1) s1[i] += wj;   // compile-time bit -> no branch
  }
  float rS = 1.f / S;
#pragma unroll
  for (int i = 0; i < NB; ++i) q[i] = 2.f * s1[i] * rS - 1.f;  // (S1-S0)/S
}

// ---------------- pack: weights -> bf16 B-fragments in ws (once) ------------
// wsF[0..32768)      : W24 frags, 32 ksteps x 2 nfrags x 64 lanes x 8
// wsF[32768..57344)  : Wf compact frags, 64 dfrags x 48 lanes x 8 (k<24)
__global__ __launch_bounds__(256) void pack_kernel(
    const float* __restrict__ w_to_l1,  const float* __restrict__ w_to_l2,
    const float* __restrict__ w_to_l3u, const float* __restrict__ w_to_l3l,
    const float* __restrict__ w_gate,
    const float* __restrict__ w_from_l1, const float* __restrict__ w_from_l2,
    const float* __restrict__ w_from_l3,
    short* __restrict__ wsF, float* __restrict__ wsA)
{
  int base = blockIdx.x*4096 + threadIdx.x*16;
#pragma unroll
  for (int q = 0; q < 16; ++q){
    int e = base + q;
    float v;
    if (e < 32768){
      int s  = e >> 10;
      int nf = (e >> 9) & 1;
      int ll = (e >> 3) & 63;
      int j  = e & 7;
      int k  = s*32 + ((ll >> 4) << 3) + j;
      int n  = nf*16 + (ll & 15);
      if      (n < 3)  v = w_gate  [k*3 + n];
      else if (n < 6)  v = w_to_l1 [k*3 + (n-3)];
      else if (n < 12) v = w_to_l2 [k*6 + (n-6)];
      else if (n < 18) v = w_to_l3u[k*6 + (n-12)];
      else if (n < 24) v = w_to_l3l[k*6 + (n-18)];
      else             v = 0.f;
    } else {
      int e2  = e - 32768;
      int f   = e2 / 384;
      int rem = e2 - f*384;
      int ll  = rem >> 3;
      int j   = e2 & 7;
      int k   = ((ll >> 4) << 3) + j;      // 0..23
      int dd  = f*16 + (ll & 15);
      if      (k < 3)  v = w_from_l1[k*DM + dd];
      else if (k < 9)  v = w_from_l2[(k-3)*DM + dd];
      else if (k < 21) v = w_from_l3[(k-9)*DM + dd];
      else             v = 0.f;
    }
    wsF[e] = f2bf(v);
  }
  if (blockIdx.x == 0){
    wsA[threadIdx.x]       = 0.f;
    wsA[threadIdx.x + 256] = 0.f;
  }
}

// ---------------- fused producer/consumer kernel ----------------------------
__global__ __launch_bounds__(512, 2) void hq11_kernel(
    const float* __restrict__ x, const short* __restrict__ wsF,
    const float* __restrict__ b_gate,
    const float* __restrict__ t1p, const float* __restrict__ t2p, const float* __restrict__ t3p,
    const float* __restrict__ s1p, const float* __restrict__ s2p, const float* __restrict__ s3p,
    float* __restrict__ wsA, float* __restrict__ out)
{
  __shared__ alignas(16) char smem[105472];

  const int tid  = threadIdx.x;
  const int l    = tid & 63;
  const int wid  = tid >> 6;       // 0..7
  const int kg   = l >> 4;
  const int ln16 = l & 15;
  const size_t tokB = (size_t)blockIdx.x * 128;   // 8 tiles of 16 tokens
  const short* wsFC = wsF + 32768;
  const bf16x8 z8 = {0,0,0,0,0,0,0,0};

  if (wid < 4){
    // ===================== PRODUCER (down-proj, K-split) =====================
    const int pw  = wid;           // covers cols [pw*256, pw*256+256)
    char* stg = smem + pw*16384;   // dbuf 2 x 8KB (128-col chunks)
    const int lr0 = l >> 5;
    const int cbp = l & 31;

    // prologue: DMA chunk 0 (tile 0, ci 0) -> buf 0
#pragma unroll
    for (int i = 0; i < 8; ++i){
      int lr = i*2 + lr0;
      gl_lds16(x + (tokB + lr)*DM + pw*256 + (cbp ^ (lr & 7))*4,
               stg + i*1024 + l*16);
    }

#pragma unroll
    for (int s = 0; s < 8; ++s){
      f32x4 acc0 = {0.f,0.f,0.f,0.f}, acc1 = {0.f,0.f,0.f,0.f};
#pragma unroll
      for (int ci = 0; ci < 2; ++ci){
        const int n = s*2 + ci;    // global chunk 0..15
        bf16x8 bfr[8];
#pragma unroll
        for (int s2 = 0; s2 < 8; ++s2)
          bfr[s2] = *reinterpret_cast<const bf16x8*>(
              &wsF[(size_t)(pw*16 + ci*8 + s2)*512 + l*8]);
        __builtin_amdgcn_sched_barrier(0);
        if (n < 15){
          const int np = n + 1, sp = np >> 1, cip = np & 1;
#pragma unroll
          for (int i = 0; i < 8; ++i){
            int lr = i*2 + lr0;
            gl_lds16(x + (tokB + sp*16 + lr)*DM + pw*256 + cip*128 + (cbp ^ (lr & 7))*4,
                     stg + (np & 1)*8192 + i*1024 + l*16);
          }
          asm volatile("s_waitcnt vmcnt(8)" ::: "memory");  // drains DMA(n)+bfr(n)
        } else {
          asm volatile("s_waitcnt vmcnt(0)" ::: "memory");
        }
        __builtin_amdgcn_sched_barrier(0);
        const char* ab = stg + (n & 1)*8192 + ln16*512;
#pragma unroll
        for (int s2 = 0; s2 < 4; ++s2){
          float4 xa = *reinterpret_cast<const float4*>(ab + (size_t)((s2*8 + kg*2 + 0) ^ (ln16 & 7))*16);
          float4 xb = *reinterpret_cast<const float4*>(ab + (size_t)((s2*8 + kg*2 + 1) ^ (ln16 & 7))*16);
          bf16x8 af;
          af[0]=f2bf(xa.x); af[1]=f2bf(xa.y); af[2]=f2bf(xa.z); af[3]=f2bf(xa.w);
          af[4]=f2bf(xb.x); af[5]=f2bf(xb.y); af[6]=f2bf(xb.z); af[7]=f2bf(xb.w);
          acc0 = __builtin_amdgcn_mfma_f32_16x16x32_bf16(af, bfr[s2*2+0], acc0, 0, 0, 0);
          acc1 = __builtin_amdgcn_mfma_f32_16x16x32_bf16(af, bfr[s2*2+1], acc1, 0, 0, 0);
        }
      }
      // P partials -> dbuf set s&1, slot pw. D: col=l&15, row(token)=kg*4+r.
      float* Pp = reinterpret_cast<float*>(smem + POFF + (s & 1)*8704) + pw*544;
#pragma unroll
      for (int r = 0; r < 4; ++r){
        Pp[(kg*4 + r)*34 + ln16]      = acc0[r];
        Pp[(kg*4 + r)*34 + 16 + ln16] = acc1[r];
      }
      asm volatile("s_waitcnt lgkmcnt(0)" ::: "memory");   // P visible pre-barrier
      __builtin_amdgcn_sched_barrier(0);
      __builtin_amdgcn_s_barrier();                        // NO vmcnt drain: DMA flows
      __builtin_amdgcn_sched_barrier(0);
    }
    // producers exit (consumers do step 8 with no further barrier)
  } else {
    // ===================== CONSUMER (quantize + epilogue) ====================
    const int cw = wid - 4;        // covers cols [cw*256, cw*256+256)
    short* Vw = reinterpret_cast<short*>(smem + VOFF + cw*1280);
    float* Cw = reinterpret_cast<float*>(smem + COFF + cw*4352);
    const int rl = l >> 2;
    const int cs = l & 3;

    const float invt1 = 1.f / fminf(fmaxf(__expf(t1p[0]), 0.01f), 5.0f);
    const float invt2 = 1.f / fminf(fmaxf(__expf(t2p[0]), 0.01f), 5.0f);
    const float invt3 = 1.f / fminf(fmaxf(__expf(t3p[0]), 0.01f), 5.0f);
    const float s1v = s1p[0], s2v = s2p[0], s3v = s3p[0];
    const float bg0 = b_gate[0], bg1 = b_gate[1], bg2 = b_gate[2];
    float sg0 = 0.f, sg1 = 0.f, sg2 = 0.f;

    // preload the 16 Wf fragments this wave ever needs (fixed across tiles)
    bf16x8 bw[4][4];
#pragma unroll
    for (int j = 0; j < 4; ++j)
#pragma unroll
      for (int ff = 0; ff < 4; ++ff){
        bw[j][ff] = z8;
        if (kg < 3)
          bw[j][ff] = *reinterpret_cast<const bf16x8*>(
              &wsFC[(size_t)((cw*4 + j)*4 + ff)*384 + l*8]);
      }

    f32x4 xc0, xc1, xc2, xc3;      // current epi x chunk (prefetched)
#pragma unroll
    for (int s = 0; s <= 8; ++s){
      if (s > 0){
        const int t = s - 1;
        if (t == 0){               // first x prefetch; latency hides under quant
          const float* xr = x + (tokB + rl)*DM + cw*256 + cs*4;
          xc0 = *reinterpret_cast<const f32x4*>(xr);
          xc1 = *reinterpret_cast<const f32x4*>(xr + 16);
          xc2 = *reinterpret_cast<const f32x4*>(xr + 32);
          xc3 = *reinterpret_cast<const f32x4*>(xr + 48);
        }
        // ---- quantize tile t (each consumer wave redundantly) ----
        {
          const int tq = ln16;
          const int gi = kg;       // 0:l2 1:l3u 2:l3l 3:gate+l1
          const int base = (gi == 3) ? 0 : 6 + gi*6;
          const float* P0 = reinterpret_cast<const float*>(smem + POFF + (t & 1)*8704);
          float z[6];
#pragma unroll
          for (int i = 0; i < 6; ++i){
            int idx = tq*34 + base + i;
            z[i] = P0[idx] + P0[544 + idx] + P0[1088 + idx] + P0[1632 + idx];
          }
          float qv[6] = {0,0,0,0,0,0};
          float myscale = 0.f, g1s2v = 0.f, g2s3v = 0.f;
          if (gi == 3){
            float g0l = z[0] + bg0;
            float g1l = z[1] + bg1;
            float g2l = z[2] + bg2;
            float m  = fmaxf(g0l, fmaxf(g1l, g2l));
            float e0 = __expf(g0l - m), e1 = __expf(g1l - m), e2 = __expf(g2l - m);
            float rs = 1.f / (e0 + e1 + e2);
            float g0 = e0*rs, g1 = e1*rs, g2 = e2*rs;
            myscale = g0 * s1v;
            g1s2v   = g1 * s2v;
            g2s3v   = g2 * s3v;
            float z1[3] = {z[3], z[4], z[5]};
            softq<3>(z1, invt1, qv);
            float a0 = g0, a1 = g1, a2 = g2;
#pragma unroll
            for (int mm = 1; mm < 16; mm <<= 1){
              a0 += __shfl_xor(a0, mm, 64);
              a1 += __shfl_xor(a1, mm, 64);
              a2 += __shfl_xor(a2, mm, 64);
            }
            sg0 += a0; sg1 += a1; sg2 += a2;
          } else {
            float invt = (gi == 0) ? invt2 : invt3;
            softq<6>(z, invt, qv);
          }
          float gs1 = __shfl(g1s2v, 48 + tq, 64);
          float gs2 = __shfl(g2s3v, 48 + tq, 64);
          if (gi == 3){
#pragma unroll
            for (int i = 0; i < 3; ++i) Vw[tq*40 + i] = f2bf(myscale * qv[i]);
            Vw[tq*40 + 21] = 0; Vw[tq*40 + 22] = 0; Vw[tq*40 + 23] = 0;
          } else {
            float sc = (gi == 0) ? gs1 : gs2;
            int voff = 3 + gi*6;
#pragma unroll
            for (int i = 0; i < 6; ++i) Vw[tq*40 + voff + i] = f2bf(sc * qv[i]);
          }
        }
        bf16x8 aV = z8;
        if (kg < 3) aV = *reinterpret_cast<const bf16x8*>(&Vw[ln16*40 + kg*8]);

        // ---- epilogue tile t: 4 x 64-col chunks, x(j+1) issued before stores(j)
#pragma unroll
        for (int j = 0; j < 4; ++j){
          f32x4 xn0 = xc0, xn1 = xc1, xn2 = xc2, xn3 = xc3;
          if (!(t == 7 && j == 3)){
            const int tn = (j < 3) ? t : t + 1;
            const int jn = (j < 3) ? j + 1 : 0;
            const float* xr = x + (tokB + tn*16 + rl)*DM + cw*256 + jn*64 + cs*4;
            xn0 = *reinterpret_cast<const f32x4*>(xr);
            xn1 = *reinterpret_cast<const f32x4*>(xr + 16);
            xn2 = *reinterpret_cast<const f32x4*>(xr + 32);
            xn3 = *reinterpret_cast<const f32x4*>(xr + 48);
          }
          __builtin_amdgcn_sched_barrier(0);
          const f32x4 zz = {0.f,0.f,0.f,0.f};
          f32x4 d0 = __builtin_amdgcn_mfma_f32_16x16x32_bf16(aV, bw[j][0], zz, 0, 0, 0);
          f32x4 d1 = __builtin_amdgcn_mfma_f32_16x16x32_bf16(aV, bw[j][1], zz, 0, 0, 0);
          f32x4 d2 = __builtin_amdgcn_mfma_f32_16x16x32_bf16(aV, bw[j][2], zz, 0, 0, 0);
          f32x4 d3 = __builtin_amdgcn_mfma_f32_16x16x32_bf16(aV, bw[j][3], zz, 0, 0, 0);
#pragma unroll
          for (int r = 0; r < 4; ++r){
            int rb = (kg*4 + r)*68;
            Cw[rb +  0 + ln16] = d0[r];
            Cw[rb + 16 + ln16] = d1[r];
            Cw[rb + 32 + ln16] = d2[r];
            Cw[rb + 48 + ln16] = d3[r];
          }
          __builtin_amdgcn_sched_barrier(0);
          f32x4 c0 = *reinterpret_cast<const f32x4*>(&Cw[rl*68 + cs*4]);
          f32x4 c1 = *reinterpret_cast<const f32x4*>(&Cw[rl*68 + cs*4 + 16]);
          f32x4 c2 = *reinterpret_cast<const f32x4*>(&Cw[rl*68 + cs*4 + 32]);
          f32x4 c3 = *reinterpret_cast<const f32x4*>(&Cw[rl*68 + cs*4 + 48]);
          float* orow = out + (tokB + t*16 + rl)*DM + cw*256 + j*64 + cs*4;
          *reinterpret_cast<f32x4*>(orow)      = xc0 + c0;
          *reinterpret_cast<f32x4*>(orow + 16) = xc1 + c1;
          *reinterpret_cast<f32x4*>(orow + 32) = xc2 + c2;
          *reinterpret_cast<f32x4*>(orow + 48) = xc3 + c3;
          __builtin_amdgcn_sched_barrier(0);
          xc0 = xn0; xc1 = xn1; xc2 = xn2; xc3 = xn3;
        }
      }
      if (s < 8){
        asm volatile("s_waitcnt lgkmcnt(0)" ::: "memory");  // P/C/V reads done
        __builtin_amdgcn_sched_barrier(0);
        __builtin_amdgcn_s_barrier();                       // stores stay in flight
        __builtin_amdgcn_sched_barrier(0);
      }
    }

    if (cw == 0 && l == 48){
      float* slot = wsA + (blockIdx.x & (NSLOT-1))*16;
      atomicAdd(slot + 0, sg0);
      atomicAdd(slot + 1, sg1);
      atomicAdd(slot + 2, sg2);
    }
  }
}

// ---------------- finalize: reduce 32 gate slots -> out[OUT_OFF..+2] --------
__global__ void finalize_kernel(const float* __restrict__ wsA, float* __restrict__ out){
  if (threadIdx.x < 3){
    float s = 0.f;
    for (int j = 0; j < NSLOT; ++j) s += wsA[j*16 + threadIdx.x];
    out[OUT_OFF + threadIdx.x] = s * (1.f / (float)NTOK);
  }
}

extern "C" void kernel_launch(void* const* d_in, const int* in_sizes, int n_in,
                              void* d_out, int out_size, void* d_ws, size_t ws_size,
                              hipStream_t stream){
  (void)in_sizes; (void)n_in; (void)ws_size; (void)out_size;
  const float* x         = (const float*)d_in[0];
  // d_in[1] (codes_l1), d_in[2] (codes_l2) unused: corners derived from bits
  const float* w_to_l1   = (const float*)d_in[3];
  const float* w_from_l1 = (const float*)d_in[4];
  const float* w_to_l2   = (const float*)d_in[5];
  const float* w_from_l2 = (const float*)d_in[6];
  const float* w_to_l3u  = (const float*)d_in[7];
  const float* w_to_l3l  = (const float*)d_in[8];
  const float* w_from_l3 = (const float*)d_in[9];
  const float* w_gate    = (const float*)d_in[10];
  const float* b_gate    = (const float*)d_in[11];
  const float* t1 = (const float*)d_in[12];
  const float* t2 = (const float*)d_in[13];
  const float* t3 = (const float*)d_in[14];
  const float* s1 = (const float*)d_in[15];
  const float* s2 = (const float*)d_in[16];
  const float* s3 = (const float*)d_in[17];
  float* out  = (float*)d_out;
  short* wsF  = (short*)d_ws;                       // 57344 shorts of fragments
  float* wsA  = (float*)d_ws + WSA_OFF;             // 32 slots x 16 floats

  pack_kernel<<<dim3(14), dim3(256), 0, stream>>>(
      w_to_l1, w_to_l2, w_to_l3u, w_to_l3l, w_gate,
      w_from_l1, w_from_l2, w_from_l3, wsF, wsA);
  hq11_kernel<<<dim3(256), dim3(512), 0, stream>>>(
      x, wsF, b_gate, t1, t2, t3, s1, s2, s3, wsA, out);
  finalize_kernel<<<dim3(1), dim3(64), 0, stream>>>(wsA, out);
}

// Round 14
// 96.368 us; speedup vs baseline: 2.4911x; 2.4911x over previous
//
#include <hip/hip_runtime.h>
#include <stdint.h>

// HierarchicalZ2_12Quantizer on MI355X (gfx950) — split: DMA-down + L3-up.
// tokens = 8*4096 = 32768, D = 1024
// R13 post-mortem: wave-level read/write mixing falsified 3 ways (occupancy/
// grid/width). R14 insight: out-stores complete at L2/L3 (memory-side cache);
// HBM writeback drains lazily, overlapping the NEXT launch/replay's reads —
// cross-launch bidirectional mixing for free. R3's split up_kernel measured
// ~15us standalone; R3's down was slow only from register-load MLP (fixed by
// R7/R10 DMA staging). R14 = R10's down (barrier-free, per-wave DMA, vmcnt(8))
// + quantize + V->ws, then R3's up_kernel verbatim.
// codes from bit patterns: c[j][i] = ((j>>(n-1-i))&1)?+1:-1.

#define DM 1024
#define OUT_OFF ((size_t)33554432)  // 8*4096*1024
#define NTOK 32768
#define NSLOT 32
#define WSV_OFF 65536               // short offset of V buffer in ws (2 MB)
#define WSA_OFFF 557056             // float offset of gate-acc (after wsV)

typedef float f32x4 __attribute__((ext_vector_type(4)));
typedef short bf16x8 __attribute__((ext_vector_type(8)));

typedef const __attribute__((address_space(1))) unsigned int* gas1_t;
typedef __attribute__((address_space(3))) unsigned int* las3_t;

__device__ __forceinline__ void gl_lds16(const void* g, void* l){
  __builtin_amdgcn_global_load_lds((gas1_t)g, (las3_t)l, 16, 0, 0);
}

__device__ __forceinline__ short f2bf(float f){
  unsigned u = __builtin_bit_cast(unsigned, f);
  unsigned r = u + 0x7fffu + ((u >> 16) & 1u);   // round-to-nearest-even
  return (short)(r >> 16);
}

// soft_quantize over the 2^NB hypercube corners; z[NB] -> q[NB]
template<int NB>
__device__ __forceinline__ void softq(const float* z, float invt, float* q){
  constexpr int K = 1 << NB;
  float d[K];
  float dmin = 3.4e38f;
#pragma unroll
  for (int j = 0; j < K; ++j){
    float acc = 0.f;
#pragma unroll
    for (int i = 0; i < NB; ++i){
      float c = ((j >> (NB-1-i)) & 1) ? 1.f : -1.f;
      float t = z[i] - c;
      acc = fmaf(t, t, acc);
    }
    float dj = sqrtf(acc);
    d[j] = dj;
    dmin = fminf(dmin, dj);
  }
  float S = 0.f;
  float s1[NB];
#pragma unroll
  for (int i = 0; i < NB; ++i) s1[i] = 0.f;
#pragma unroll
  for (int j = 0; j < K; ++j){
    float wj = __expf((dmin - d[j]) * invt);
    S += wj;
#pragma unroll
    for (int i = 0; i < NB; ++i)
      if ((j >> (NB-1-i)) & 1) s1[i] += wj;   // compile-time bit -> no branch
  }
  float rS = 1.f / S;
#pragma unroll
  for (int i = 0; i < NB; ++i) q[i] = 2.f * s1[i] * rS - 1.f;  // (S1-S0)/S
}

// ---------------- pack: weights -> bf16 B-fragments in ws (once) ------------
// wsF[0..32768)      : W24 frags, 32 ksteps x 2 nfrags x 64 lanes x 8
// wsF[32768..57344)  : Wf compact frags, 64 dfrags x 48 lanes x 8 (k<24)
__global__ __launch_bounds__(256) void pack_kernel(
    const float* __restrict__ w_to_l1,  const float* __restrict__ w_to_l2,
    const float* __restrict__ w_to_l3u, const float* __restrict__ w_to_l3l,
    const float* __restrict__ w_gate,
    const float* __restrict__ w_from_l1, const float* __restrict__ w_from_l2,
    const float* __restrict__ w_from_l3,
    short* __restrict__ wsF, float* __restrict__ wsA)
{
  int base = blockIdx.x*4096 + threadIdx.x*16;
#pragma unroll
  for (int q = 0; q < 16; ++q){
    int e = base + q;
    float v;
    if (e < 32768){
      int s  = e >> 10;
      int nf = (e >> 9) & 1;
      int ll = (e >> 3) & 63;
      int j  = e & 7;
      int k  = s*32 + ((ll >> 4) << 3) + j;
      int n  = nf*16 + (ll & 15);
      if      (n < 3)  v = w_gate  [k*3 + n];
      else if (n < 6)  v = w_to_l1 [k*3 + (n-3)];
      else if (n < 12) v = w_to_l2 [k*6 + (n-6)];
      else if (n < 18) v = w_to_l3u[k*6 + (n-12)];
      else if (n < 24) v = w_to_l3l[k*6 + (n-18)];
      else             v = 0.f;
    } else {
      int e2  = e - 32768;
      int f   = e2 / 384;
      int rem = e2 - f*384;
      int ll  = rem >> 3;
      int j   = e2 & 7;
      int k   = ((ll >> 4) << 3) + j;      // 0..23
      int dd  = f*16 + (ll & 15);
      if      (k < 3)  v = w_from_l1[k*DM + dd];
      else if (k < 9)  v = w_from_l2[(k-3)*DM + dd];
      else if (k < 21) v = w_from_l3[(k-9)*DM + dd];
      else             v = 0.f;
    }
    wsF[e] = f2bf(v);
  }
  if (blockIdx.x == 0){
    wsA[threadIdx.x]       = 0.f;
    wsA[threadIdx.x + 256] = 0.f;
  }
}

// ---- quantize 16 tokens, wave-local, lane group = role (accumulates sg) ----
__device__ __forceinline__ void quant16(const float* Pw, short* Vw, int l,
    float invt1, float invt2, float invt3, float s1v, float s2v, float s3v,
    float bg0, float bg1, float bg2, float& sg0, float& sg1, float& sg2)
{
  const int t  = l & 15;
  const int gi = l >> 4;   // 0:l2  1:l3u  2:l3l  3:gate+l1
  const int base = (gi == 3) ? 0 : 6 + gi*6;
  float z[6];
#pragma unroll
  for (int i = 0; i < 6; ++i) z[i] = Pw[t*34 + base + i];
  float qv[6] = {0,0,0,0,0,0};
  float myscale = 0.f, g1s2v = 0.f, g2s3v = 0.f;
  if (gi == 3){
    float g0l = z[0] + bg0;
    float g1l = z[1] + bg1;
    float g2l = z[2] + bg2;
    float m  = fmaxf(g0l, fmaxf(g1l, g2l));
    float e0 = __expf(g0l - m), e1 = __expf(g1l - m), e2 = __expf(g2l - m);
    float rs = 1.f / (e0 + e1 + e2);
    float g0 = e0*rs, g1 = e1*rs, g2 = e2*rs;
    myscale = g0 * s1v;
    g1s2v   = g1 * s2v;
    g2s3v   = g2 * s3v;
    float z1[3] = {z[3], z[4], z[5]};
    softq<3>(z1, invt1, qv);
    float a0 = g0, a1 = g1, a2 = g2;
#pragma unroll
    for (int mm = 1; mm < 16; mm <<= 1){
      a0 += __shfl_xor(a0, mm, 64);
      a1 += __shfl_xor(a1, mm, 64);
      a2 += __shfl_xor(a2, mm, 64);
    }
    sg0 += a0; sg1 += a1; sg2 += a2;
  } else {
    float invt = (gi == 0) ? invt2 : invt3;
    softq<6>(z, invt, qv);
  }
  float gs1 = __shfl(g1s2v, 48 + t, 64);
  float gs2 = __shfl(g2s3v, 48 + t, 64);
  if (gi == 3){
#pragma unroll
    for (int i = 0; i < 3; ++i) Vw[t*40 + i] = f2bf(myscale * qv[i]);
    Vw[t*40 + 21] = 0; Vw[t*40 + 22] = 0; Vw[t*40 + 23] = 0;  // kg=2 tail
  } else {
    float sc = (gi == 0) ? gs1 : gs2;
    int voff = 3 + gi*6;
#pragma unroll
    for (int i = 0; i < 6; ++i) Vw[t*40 + voff + i] = f2bf(sc * qv[i]);
  }
}

// ---------------- down: x @ W24 -> quantize -> wsV (barrier-free, DMA) ------
__global__ __launch_bounds__(256, 2) void down_kernel(
    const float* __restrict__ x, const short* __restrict__ wsF,
    const float* __restrict__ b_gate,
    const float* __restrict__ t1p, const float* __restrict__ t2p, const float* __restrict__ t3p,
    const float* __restrict__ s1p, const float* __restrict__ s2p, const float* __restrict__ s3p,
    float* __restrict__ wsA, short* __restrict__ wsV)
{
  // 16 KB strictly per wave; no cross-wave LDS, no __syncthreads.
  __shared__ alignas(16) char smem[65536];

  const int tid  = threadIdx.x;
  const int l    = tid & 63;
  const int wv   = tid >> 6;
  const int kg   = l >> 4;
  const int ln16 = l & 15;
  const size_t tokBase = (size_t)blockIdx.x*64 + wv*16;

  char*  W  = smem + wv*16384;
  float* Pw = reinterpret_cast<float*>(W + 12544);   // [16][34] f32 (overlay)
  short* Vw = reinterpret_cast<short*>(W + 14720);   // [16][40] bf16 (overlay)

  const float invt1 = 1.f / fminf(fmaxf(__expf(t1p[0]), 0.01f), 5.0f);
  const float invt2 = 1.f / fminf(fmaxf(__expf(t2p[0]), 0.01f), 5.0f);
  const float invt3 = 1.f / fminf(fmaxf(__expf(t3p[0]), 0.01f), 5.0f);
  const float s1v = s1p[0], s2v = s2p[0], s3v = s3p[0];
  const float bg0 = b_gate[0], bg1 = b_gate[1], bg2 = b_gate[2];
  float sg0 = 0.f, sg1 = 0.f, sg2 = 0.f;

  // down-proj: per-wave dbuf DMA, vmcnt(8) ledger (R10-proven)
  {
    f32x4 acc0 = {0.f,0.f,0.f,0.f}, acc1 = {0.f,0.f,0.f,0.f};
    const int lr0 = l >> 5;
    const int cbp = l & 31;
#pragma unroll
    for (int i = 0; i < 8; ++i){
      int lr = i*2 + lr0;
      gl_lds16(x + (tokBase + lr)*DM + (cbp ^ (lr & 7))*4, W + i*1024 + l*16);
    }
#pragma unroll
    for (int t = 0; t < 8; ++t){
      const int buf = t & 1;
      bf16x8 bfr[8];
#pragma unroll
      for (int s2 = 0; s2 < 8; ++s2)
        bfr[s2] = *reinterpret_cast<const bf16x8*>(&wsF[(t*8 + s2)*512 + l*8]);
      __builtin_amdgcn_sched_barrier(0);
      if (t < 7){
#pragma unroll
        for (int i = 0; i < 8; ++i){
          int lr = i*2 + lr0;
          gl_lds16(x + (tokBase + lr)*DM + (t+1)*128 + (cbp ^ (lr & 7))*4,
                   W + (buf^1)*8192 + i*1024 + l*16);
        }
        asm volatile("s_waitcnt vmcnt(8)" ::: "memory");
      } else {
        asm volatile("s_waitcnt vmcnt(0)" ::: "memory");
      }
      __builtin_amdgcn_sched_barrier(0);
      const char* abase = W + buf*8192 + ln16*512;
#pragma unroll
      for (int s = 0; s < 4; ++s){
        float4 xa = *reinterpret_cast<const float4*>(abase + ((s*8 + kg*2 + 0) ^ (ln16 & 7))*16);
        float4 xb = *reinterpret_cast<const float4*>(abase + ((s*8 + kg*2 + 1) ^ (ln16 & 7))*16);
        bf16x8 af;
        af[0]=f2bf(xa.x); af[1]=f2bf(xa.y); af[2]=f2bf(xa.z); af[3]=f2bf(xa.w);
        af[4]=f2bf(xb.x); af[5]=f2bf(xb.y); af[6]=f2bf(xb.z); af[7]=f2bf(xb.w);
        acc0 = __builtin_amdgcn_mfma_f32_16x16x32_bf16(af, bfr[s*2+0], acc0, 0, 0, 0);
        acc1 = __builtin_amdgcn_mfma_f32_16x16x32_bf16(af, bfr[s*2+1], acc1, 0, 0, 0);
      }
    }
#pragma unroll
    for (int r = 0; r < 4; ++r){      // D: col = l&15, row(token) = kg*4 + r
      int row = kg*4 + r;
      Pw[row*34 + ln16]      = acc0[r];
      Pw[row*34 + 16 + ln16] = acc1[r];
    }
  }

  // quantize (wave-local) -> Vw, then coalesced copy to wsV (cols 24-31 zero)
  quant16(Pw, Vw, l, invt1, invt2, invt3, s1v, s2v, s3v, bg0, bg1, bg2, sg0, sg1, sg2);
  {
    int row = l >> 2, seg = l & 3;
    bf16x8 v = {0,0,0,0,0,0,0,0};
    if (seg < 3) v = *reinterpret_cast<const bf16x8*>(&Vw[row*40 + seg*8]);
    *reinterpret_cast<bf16x8*>(&wsV[(tokBase + row)*32 + seg*8]) = v;
  }

  if (l == 48){
    float* slot = wsA + ((blockIdx.x*4 + wv) & (NSLOT-1))*16;
    atomicAdd(slot + 0, sg0);
    atomicAdd(slot + 1, sg1);
    atomicAdd(slot + 2, sg2);
  }
}

// ---------------- up: V @ Wf + residual (R3-measured ~15us structure) -------
__global__ __launch_bounds__(256) void up_kernel(
    const short* __restrict__ wsF, const short* __restrict__ wsV,
    const float* __restrict__ x, float* __restrict__ out)
{
  __shared__ float C[64*68];                // corr chunk [64][68] (17.4 KB)

  const int tid  = threadIdx.x;
  const int l    = tid & 63;
  const int wv   = tid >> 6;
  const int kg   = l >> 4;
  const int ln16 = l & 15;
  const int tb   = blockIdx.x * 64;
  const short* wsFC = wsF + 32768;

  // A-fragment: V row slice straight from ws
  bf16x8 aV = {0,0,0,0,0,0,0,0};
  if (kg < 3)
    aV = *reinterpret_cast<const bf16x8*>(&wsV[(size_t)(tb + wv*16 + ln16)*32 + kg*8]);

  const f32x4 z4 = {0.f,0.f,0.f,0.f};
  const int rrow = tid >> 4;        // 0..15
  const int rcol = (tid & 15) * 4;  // 0..60

#pragma unroll 1
  for (int c = 0; c < 16; ++c){
    // hoist x loads for this chunk (L2/L3-hot after down_kernel)
    float4 xv[4];
#pragma unroll
    for (int p = 0; p < 4; ++p){
      int row = p*16 + rrow;
      xv[p] = *reinterpret_cast<const float4*>(&x[(size_t)(tb + row)*DM + c*64 + rcol]);
    }
    // 64-col chunk: 4 MFMA per wave -> C
#pragma unroll
    for (int ff = 0; ff < 4; ++ff){
      bf16x8 bfr = {0,0,0,0,0,0,0,0};
      if (kg < 3)
        bfr = *reinterpret_cast<const bf16x8*>(&wsFC[(c*4+ff)*384 + l*8]);
      f32x4 dd = __builtin_amdgcn_mfma_f32_16x16x32_bf16(aV, bfr, z4, 0, 0, 0);
#pragma unroll
      for (int r = 0; r < 4; ++r)
        C[(wv*16 + kg*4 + r)*68 + ff*16 + ln16] = dd[r];
    }
    __syncthreads();
    // coalesced residual pass: full 256B lines per 16-lane group
#pragma unroll
    for (int p = 0; p < 4; ++p){
      int row = p*16 + rrow;
      float4 cv = *reinterpret_cast<const float4*>(&C[row*68 + rcol]);
      float4 ov;
      ov.x = xv[p].x + cv.x; ov.y = xv[p].y + cv.y;
      ov.z = xv[p].z + cv.z; ov.w = xv[p].w + cv.w;
      *reinterpret_cast<float4*>(&out[(size_t)(tb + row)*DM + c*64 + rcol]) = ov;
    }
    __syncthreads();
  }
}

// ---------------- finalize: reduce 32 gate slots -> out[OUT_OFF..+2] --------
__global__ void finalize_kernel(const float* __restrict__ wsA, float* __restrict__ out){
  if (threadIdx.x < 3){
    float s = 0.f;
    for (int j = 0; j < NSLOT; ++j) s += wsA[j*16 + threadIdx.x];
    out[OUT_OFF + threadIdx.x] = s * (1.f / (float)NTOK);
  }
}

extern "C" void kernel_launch(void* const* d_in, const int* in_sizes, int n_in,
                              void* d_out, int out_size, void* d_ws, size_t ws_size,
                              hipStream_t stream){
  (void)in_sizes; (void)n_in; (void)ws_size; (void)out_size;
  const float* x         = (const float*)d_in[0];
  // d_in[1] (codes_l1), d_in[2] (codes_l2) unused: corners derived from bits
  const float* w_to_l1   = (const float*)d_in[3];
  const float* w_from_l1 = (const float*)d_in[4];
  const float* w_to_l2   = (const float*)d_in[5];
  const float* w_from_l2 = (const float*)d_in[6];
  const float* w_to_l3u  = (const float*)d_in[7];
  const float* w_to_l3l  = (const float*)d_in[8];
  const float* w_from_l3 = (const float*)d_in[9];
  const float* w_gate    = (const float*)d_in[10];
  const float* b_gate    = (const float*)d_in[11];
  const float* t1 = (const float*)d_in[12];
  const float* t2 = (const float*)d_in[13];
  const float* t3 = (const float*)d_in[14];
  const float* s1 = (const float*)d_in[15];
  const float* s2 = (const float*)d_in[16];
  const float* s3 = (const float*)d_in[17];
  float* out  = (float*)d_out;
  short* wsF  = (short*)d_ws;                       // 57344 shorts of fragments
  short* wsV  = (short*)d_ws + WSV_OFF;             // 32768 x 32 bf16 = 2 MB
  float* wsA  = (float*)d_ws + WSA_OFFF;            // 32 slots x 16 floats

  pack_kernel<<<dim3(14), dim3(256), 0, stream>>>(
      w_to_l1, w_to_l2, w_to_l3u, w_to_l3l, w_gate,
      w_from_l1, w_from_l2, w_from_l3, wsF, wsA);
  down_kernel<<<dim3(512), dim3(256), 0, stream>>>(
      x, wsF, b_gate, t1, t2, t3, s1, s2, s3, wsA, wsV);
  up_kernel<<<dim3(512), dim3(256), 0, stream>>>(
      wsF, wsV, x, out);
  finalize_kernel<<<dim3(1), dim3(64), 0, stream>>>(wsA, out);
}

// Round 15
// 81.036 us; speedup vs baseline: 2.9624x; 1.1892x over previous
//
#include <hip/hip_runtime.h>
#include <stdint.h>

// HierarchicalZ2_12Quantizer on MI355X (gfx950) — R9 structure, plain-load epi.
// tokens = 8*4096 = 32768, D = 1024
// R14 post-mortem: kernel-split regressed (96us) and showed the read phase is
// latency-structured, not BW-bound; fused R9 (79.4us) is the proven best.
// R15 = R9 with ONE change: epilogue x comes from plain L2-hot float4 loads
// (no epi DMA, no epi vmcnt asm — compiler waits only; stores stay newest).
// Down keeps the proven per-wave DMA dbuf + vmcnt(8) ledger.
// codes from bit patterns: c[j][i] = ((j>>(n-1-i))&1)?+1:-1.

#define DM 1024
#define TPB 64
#define OUT_OFF ((size_t)33554432)  // 8*4096*1024
#define NTOK 32768
#define NSLOT 32
#define WSA_OFF 32768               // float offset of gate-acc in ws

typedef float f32x4 __attribute__((ext_vector_type(4)));
typedef short bf16x8 __attribute__((ext_vector_type(8)));

typedef const __attribute__((address_space(1))) unsigned int* gas1_t;
typedef __attribute__((address_space(3))) unsigned int* las3_t;

__device__ __forceinline__ void gl_lds16(const void* g, void* l){
  __builtin_amdgcn_global_load_lds((gas1_t)g, (las3_t)l, 16, 0, 0);
}

__device__ __forceinline__ short f2bf(float f){
  unsigned u = __builtin_bit_cast(unsigned, f);
  unsigned r = u + 0x7fffu + ((u >> 16) & 1u);   // round-to-nearest-even
  return (short)(r >> 16);
}

// soft_quantize over the 2^NB hypercube corners; z[NB] -> q[NB]
template<int NB>
__device__ __forceinline__ void softq(const float* z, float invt, float* q){
  constexpr int K = 1 << NB;
  float d[K];
  float dmin = 3.4e38f;
#pragma unroll
  for (int j = 0; j < K; ++j){
    float acc = 0.f;
#pragma unroll
    for (int i = 0; i < NB; ++i){
      float c = ((j >> (NB-1-i)) & 1) ? 1.f : -1.f;
      float t = z[i] - c;
      acc = fmaf(t, t, acc);
    }
    float dj = sqrtf(acc);
    d[j] = dj;
    dmin = fminf(dmin, dj);
  }
  float S = 0.f;
  float s1[NB];
#pragma unroll
  for (int i = 0; i < NB; ++i) s1[i] = 0.f;
#pragma unroll
  for (int j = 0; j < K; ++j){
    float wj = __expf((dmin - d[j]) * invt);
    S += wj;
#pragma unroll
    for (int i = 0; i < NB; ++i)
      if ((j >> (NB-1-i)) & 1) s1[i] += wj;   // compile-time bit -> no branch
  }
  float rS = 1.f / S;
#pragma unroll
  for (int i = 0; i < NB; ++i) q[i] = 2.f * s1[i] * rS - 1.f;  // (S1-S0)/S
}

// ---------------- pack: weights -> bf16 B-fragments in ws (once) ------------
// wsF[0..32768)      : W24 frags, 32 ksteps x 2 nfrags x 64 lanes x 8
// wsF[32768..57344)  : Wf compact frags, 64 dfrags x 48 lanes x 8 (k<24)
__global__ __launch_bounds__(256) void pack_kernel(
    const float* __restrict__ w_to_l1,  const float* __restrict__ w_to_l2,
    const float* __restrict__ w_to_l3u, const float* __restrict__ w_to_l3l,
    const float* __restrict__ w_gate,
    const float* __restrict__ w_from_l1, const float* __restrict__ w_from_l2,
    const float* __restrict__ w_from_l3,
    short* __restrict__ wsF, float* __restrict__ wsA)
{
  int base = blockIdx.x*4096 + threadIdx.x*16;
#pragma unroll
  for (int q = 0; q < 16; ++q){
    int e = base + q;
    float v;
    if (e < 32768){
      int s  = e >> 10;
      int nf = (e >> 9) & 1;
      int ll = (e >> 3) & 63;
      int j  = e & 7;
      int k  = s*32 + ((ll >> 4) << 3) + j;
      int n  = nf*16 + (ll & 15);
      if      (n < 3)  v = w_gate  [k*3 + n];
      else if (n < 6)  v = w_to_l1 [k*3 + (n-3)];
      else if (n < 12) v = w_to_l2 [k*6 + (n-6)];
      else if (n < 18) v = w_to_l3u[k*6 + (n-12)];
      else if (n < 24) v = w_to_l3l[k*6 + (n-18)];
      else             v = 0.f;
    } else {
      int e2  = e - 32768;
      int f   = e2 / 384;
      int rem = e2 - f*384;
      int ll  = rem >> 3;
      int j   = e2 & 7;
      int k   = ((ll >> 4) << 3) + j;      // 0..23
      int dd  = f*16 + (ll & 15);
      if      (k < 3)  v = w_from_l1[k*DM + dd];
      else if (k < 9)  v = w_from_l2[(k-3)*DM + dd];
      else if (k < 21) v = w_from_l3[(k-9)*DM + dd];
      else             v = 0.f;
    }
    wsF[e] = f2bf(v);
  }
  if (blockIdx.x == 0){
    wsA[threadIdx.x]       = 0.f;
    wsA[threadIdx.x + 256] = 0.f;
  }
}

// ---------------- fused: down (DMA) + quantize + up (plain-load epi) --------
__global__ __launch_bounds__(256, 2) void hq12_kernel(
    const float* __restrict__ x, const short* __restrict__ wsF,
    const float* __restrict__ b_gate,
    const float* __restrict__ t1p, const float* __restrict__ t2p, const float* __restrict__ t3p,
    const float* __restrict__ s1p, const float* __restrict__ s2p, const float* __restrict__ s3p,
    float* __restrict__ wsA, float* __restrict__ out)
{
  // LDS map (80576 B, 2 blocks/CU):
  //  [0,65536)      down: xb[wv][buf][16][128] f32 (per-wave dbuf; dead in epi)
  //  [49152,66560)  epi:  C[64][68] f32 (overlaps dead down tail)
  //  [66560,75264)  P[64][34] f32
  //  [75264,80384)  V16[64][40] bf16
  //  [80384,80576)  GS[64][3] f32
  __shared__ alignas(16) char smem[80576];
  float* C   = reinterpret_cast<float*>(smem + 49152);
  float* P   = reinterpret_cast<float*>(smem + 66560);
  short* V16 = reinterpret_cast<short*>(smem + 75264);
  float* GS  = reinterpret_cast<float*>(smem + 80384);

  const int tid  = threadIdx.x;
  const int l    = tid & 63;
  const int wv   = tid >> 6;    // wave 0..3, owns tokens [wv*16, wv*16+16)
  const int kg   = l >> 4;
  const int ln16 = l & 15;
  const int tb   = blockIdx.x * TPB;

  // ================= down-proj: P = x @ W24 (per-wave DMA dbuf) =============
  {
    f32x4 acc0 = {0.f,0.f,0.f,0.f}, acc1 = {0.f,0.f,0.f,0.f};
    const int lr0 = l >> 5;     // 0/1
    const int cbp = l & 31;     // 16B-block within 512B row
#pragma unroll
    for (int i = 0; i < 8; ++i){
      int lr = i*2 + lr0;
      gl_lds16(x + (size_t)(tb + wv*16 + lr)*DM + (cbp ^ (lr & 7))*4,
               smem + wv*16384 + i*1024 + l*16);
    }
#pragma unroll
    for (int t = 0; t < 8; ++t){
      const int buf = t & 1;
      // B-frags FIRST (older than next stage -> vmcnt(8) covers them)
      bf16x8 bfr[8];
#pragma unroll
      for (int s2 = 0; s2 < 8; ++s2)
        bfr[s2] = *reinterpret_cast<const bf16x8*>(&wsF[(t*8 + s2)*512 + l*8]);
      __builtin_amdgcn_sched_barrier(0);
      if (t < 7){
#pragma unroll
        for (int i = 0; i < 8; ++i){
          int lr = i*2 + lr0;
          gl_lds16(x + (size_t)(tb + wv*16 + lr)*DM + (t+1)*128 + (cbp ^ (lr & 7))*4,
                   smem + wv*16384 + (buf^1)*8192 + i*1024 + l*16);
        }
        asm volatile("s_waitcnt vmcnt(8)" ::: "memory");
      } else {
        asm volatile("s_waitcnt vmcnt(0)" ::: "memory");
      }
      const char* abase = smem + wv*16384 + buf*8192 + ln16*512;
#pragma unroll
      for (int s = 0; s < 4; ++s){
        float4 xa = *reinterpret_cast<const float4*>(abase + ((s*8 + kg*2 + 0) ^ (ln16 & 7))*16);
        float4 xb = *reinterpret_cast<const float4*>(abase + ((s*8 + kg*2 + 1) ^ (ln16 & 7))*16);
        bf16x8 af;
        af[0]=f2bf(xa.x); af[1]=f2bf(xa.y); af[2]=f2bf(xa.z); af[3]=f2bf(xa.w);
        af[4]=f2bf(xb.x); af[5]=f2bf(xb.y); af[6]=f2bf(xb.z); af[7]=f2bf(xb.w);
        acc0 = __builtin_amdgcn_mfma_f32_16x16x32_bf16(af, bfr[s*2+0], acc0, 0, 0, 0);
        acc1 = __builtin_amdgcn_mfma_f32_16x16x32_bf16(af, bfr[s*2+1], acc1, 0, 0, 0);
      }
    }
#pragma unroll
    for (int r = 0; r < 4; ++r){      // D: col = l&15, row = kg*4 + r
      int row = wv*16 + kg*4 + r;
      P[row*34 + ln16]      = acc0[r];
      P[row*34 + 16 + ln16] = acc1[r];
    }
  }
  __syncthreads();   // P complete; down x-buffers dead

  // ================= quantize (no vmem ops; gate sums stay in regs) =========
  float qv[6] = {0,0,0,0,0,0};
  float myscale = 0.f;
  float sg0 = 0.f, sg1 = 0.f, sg2 = 0.f;
  {
    const int t = l;
    const int base = (wv == 3) ? 0 : 6 + wv*6;
    float z[6];
#pragma unroll
    for (int i = 0; i < 6; ++i) z[i] = P[t*34 + base + i];
    if (wv == 3){
      float invt1 = 1.f / fminf(fmaxf(__expf(t1p[0]), 0.01f), 5.0f);
      float g0l = z[0] + b_gate[0];
      float g1l = z[1] + b_gate[1];
      float g2l = z[2] + b_gate[2];
      float m  = fmaxf(g0l, fmaxf(g1l, g2l));
      float e0 = __expf(g0l - m), e1 = __expf(g1l - m), e2 = __expf(g2l - m);
      float rs = 1.f / (e0 + e1 + e2);
      float g0 = e0*rs, g1 = e1*rs, g2 = e2*rs;
      GS[t*3+0] = g0 * s1p[0];
      GS[t*3+1] = g1 * s2p[0];
      GS[t*3+2] = g2 * s3p[0];
      myscale   = g0 * s1p[0];
      float z1[3] = {z[3], z[4], z[5]};
      softq<3>(z1, invt1, qv);
      sg0 = g0; sg1 = g1; sg2 = g2;
#pragma unroll
      for (int mm = 1; mm < 64; mm <<= 1){
        sg0 += __shfl_xor(sg0, mm, 64);
        sg1 += __shfl_xor(sg1, mm, 64);
        sg2 += __shfl_xor(sg2, mm, 64);
      }
    } else {
      float tl = (wv == 0) ? t2p[0] : t3p[0];
      float invt = 1.f / fminf(fmaxf(__expf(tl), 0.01f), 5.0f);
      softq<6>(z, invt, qv);
    }
  }
  __syncthreads();   // GS visible

  // V writes (gate-scaled bf16). cols: l1 0..2, l2 3..8, l3u 9..14, l3l 15..20
  {
    const int t = l;
    if (wv == 3){
#pragma unroll
      for (int i = 0; i < 3; ++i) V16[t*40 + i] = f2bf(myscale * qv[i]);
      V16[t*40 + 21] = 0; V16[t*40 + 22] = 0; V16[t*40 + 23] = 0;  // kg=2 tail
    } else {
      float sc = GS[t*3 + ((wv == 0) ? 1 : 2)];
      int voff = 3 + wv*6;
#pragma unroll
      for (int i = 0; i < 6; ++i) V16[t*40 + voff + i] = f2bf(sc * qv[i]);
    }
  }
  __syncthreads();   // V complete

  // ================= up-proj + residual, 16 col-chunks of 64 ================
  // Plain L2-hot loads (x re-read hits L2/L3 after down), NO epi vmcnt asm:
  // compiler inserts waits for loads only; stores are never explicitly waited.
  bf16x8 aV = {0,0,0,0,0,0,0,0};
  if (kg < 3)
    aV = *reinterpret_cast<const bf16x8*>(&V16[(wv*16 + ln16)*40 + kg*8]);
  const short* wsFC = wsF + 32768;
  const f32x4 z4 = {0.f,0.f,0.f,0.f};
  const int rl = l >> 2;        // row within wave's 16
  const int cs = l & 3;         // col-seg

  // prologue: chunk-0 frags + x
  bf16x8 bwc0={0,0,0,0,0,0,0,0}, bwc1=bwc0, bwc2=bwc0, bwc3=bwc0;
  if (kg < 3){
    bwc0 = *reinterpret_cast<const bf16x8*>(&wsFC[0*384 + l*8]);
    bwc1 = *reinterpret_cast<const bf16x8*>(&wsFC[1*384 + l*8]);
    bwc2 = *reinterpret_cast<const bf16x8*>(&wsFC[2*384 + l*8]);
    bwc3 = *reinterpret_cast<const bf16x8*>(&wsFC[3*384 + l*8]);
  }
  f32x4 xv0, xv1, xv2, xv3;
  {
    const float* xr = x + (size_t)(tb + wv*16 + rl)*DM + cs*4;
    xv0 = *reinterpret_cast<const f32x4*>(xr);
    xv1 = *reinterpret_cast<const f32x4*>(xr + 16);
    xv2 = *reinterpret_cast<const f32x4*>(xr + 32);
    xv3 = *reinterpret_cast<const f32x4*>(xr + 48);
  }

#pragma unroll
  for (int c = 0; c < 16; ++c){
    // MFMA -> C (wave-local rows, stride 68)
    {
      f32x4 d0 = __builtin_amdgcn_mfma_f32_16x16x32_bf16(aV, bwc0, z4, 0, 0, 0);
      f32x4 d1 = __builtin_amdgcn_mfma_f32_16x16x32_bf16(aV, bwc1, z4, 0, 0, 0);
      f32x4 d2 = __builtin_amdgcn_mfma_f32_16x16x32_bf16(aV, bwc2, z4, 0, 0, 0);
      f32x4 d3 = __builtin_amdgcn_mfma_f32_16x16x32_bf16(aV, bwc3, z4, 0, 0, 0);
#pragma unroll
      for (int r = 0; r < 4; ++r){
        int rowb = (wv*16 + kg*4 + r)*68;
        C[rowb +  0 + ln16] = d0[r];
        C[rowb + 16 + ln16] = d1[r];
        C[rowb + 32 + ln16] = d2[r];
        C[rowb + 48 + ln16] = d3[r];
      }
    }
    __builtin_amdgcn_sched_barrier(0);
    // prefetch next chunk's frags + x (issued before this chunk's stores)
    bf16x8 bwn0 = bwc0, bwn1 = bwc1, bwn2 = bwc2, bwn3 = bwc3;
    f32x4 xn0 = xv0, xn1 = xv1, xn2 = xv2, xn3 = xv3;
    if (c < 15){
      if (kg < 3){
        bwn0 = *reinterpret_cast<const bf16x8*>(&wsFC[((c+1)*4+0)*384 + l*8]);
        bwn1 = *reinterpret_cast<const bf16x8*>(&wsFC[((c+1)*4+1)*384 + l*8]);
        bwn2 = *reinterpret_cast<const bf16x8*>(&wsFC[((c+1)*4+2)*384 + l*8]);
        bwn3 = *reinterpret_cast<const bf16x8*>(&wsFC[((c+1)*4+3)*384 + l*8]);
      }
      const float* xr = x + (size_t)(tb + wv*16 + rl)*DM + (c+1)*64 + cs*4;
      xn0 = *reinterpret_cast<const f32x4*>(xr);
      xn1 = *reinterpret_cast<const f32x4*>(xr + 16);
      xn2 = *reinterpret_cast<const f32x4*>(xr + 32);
      xn3 = *reinterpret_cast<const f32x4*>(xr + 48);
    }
    __builtin_amdgcn_sched_barrier(0);
    asm volatile("s_waitcnt lgkmcnt(0)" ::: "memory");   // C visible (same wave)
    __builtin_amdgcn_sched_barrier(0);
    // residual pass: coalesced f4 stores (64B runs), newest vmem ops
#pragma unroll
    for (int q = 0; q < 4; ++q){
      int bi = cs + 4*q;
      f32x4 cv = *reinterpret_cast<const f32x4*>(&C[(wv*16 + rl)*68 + bi*4]);
      f32x4 xq = (q == 0) ? xv0 : (q == 1) ? xv1 : (q == 2) ? xv2 : xv3;
      f32x4 ov = xq + cv;
      *reinterpret_cast<f32x4*>(&out[(size_t)(tb + wv*16 + rl)*DM + c*64 + bi*4]) = ov;
    }
    bwc0 = bwn0; bwc1 = bwn1; bwc2 = bwn2; bwc3 = bwn3;
    xv0 = xn0; xv1 = xn1; xv2 = xn2; xv3 = xn3;
  }

  // gate sums -> spread ws slots (after the loop; outside any counted waits)
  if (wv == 3 && l == 0){
    float* slot = wsA + (blockIdx.x & (NSLOT-1))*16;
    atomicAdd(slot + 0, sg0);
    atomicAdd(slot + 1, sg1);
    atomicAdd(slot + 2, sg2);
  }
}

// ---------------- finalize: reduce 32 gate slots -> out[OUT_OFF..+2] --------
__global__ void finalize_kernel(const float* __restrict__ wsA, float* __restrict__ out){
  if (threadIdx.x < 3){
    float s = 0.f;
    for (int j = 0; j < NSLOT; ++j) s += wsA[j*16 + threadIdx.x];
    out[OUT_OFF + threadIdx.x] = s * (1.f / (float)NTOK);
  }
}

extern "C" void kernel_launch(void* const* d_in, const int* in_sizes, int n_in,
                              void* d_out, int out_size, void* d_ws, size_t ws_size,
                              hipStream_t stream){
  (void)in_sizes; (void)n_in; (void)ws_size; (void)out_size;
  const float* x         = (const float*)d_in[0];
  // d_in[1] (codes_l1), d_in[2] (codes_l2) unused: corners derived from bits
  const float* w_to_l1   = (const float*)d_in[3];
  const float* w_from_l1 = (const float*)d_in[4];
  const float* w_to_l2   = (const float*)d_in[5];
  const float* w_from_l2 = (const float*)d_in[6];
  const float* w_to_l3u  = (const float*)d_in[7];
  const float* w_to_l3l  = (const float*)d_in[8];
  const float* w_from_l3 = (const float*)d_in[9];
  const float* w_gate    = (const float*)d_in[10];
  const float* b_gate    = (const float*)d_in[11];
  const float* t1 = (const float*)d_in[12];
  const float* t2 = (const float*)d_in[13];
  const float* t3 = (const float*)d_in[14];
  const float* s1 = (const float*)d_in[15];
  const float* s2 = (const float*)d_in[16];
  const float* s3 = (const float*)d_in[17];
  float* out  = (float*)d_out;
  short* wsF  = (short*)d_ws;                       // 57344 shorts of fragments
  float* wsA  = (float*)d_ws + WSA_OFF;             // 32 slots x 16 floats

  pack_kernel<<<dim3(14), dim3(256), 0, stream>>>(
      w_to_l1, w_to_l2, w_to_l3u, w_to_l3l, w_gate,
      w_from_l1, w_from_l2, w_from_l3, wsF, wsA);
  hq12_kernel<<<dim3(512), dim3(256), 0, stream>>>(
      x, wsF, b_gate, t1, t2, t3, s1, s2, s3, wsA, out);
  finalize_kernel<<<dim3(1), dim3(64), 0, stream>>>(wsA, out);
}